// Round 1
// baseline (2450.504 us; speedup 1.0000x reference)
//
#include <hip/hip_runtime.h>

#define NN 8192
#define TT 60
#define DF 6
#define HH 64
#define GG 256   // 4*H

__device__ __forceinline__ float sigmoidf_(float x) { return 1.0f / (1.0f + __expf(-x)); }
__device__ __forceinline__ float tanhf_(float x)    { return 2.0f / (1.0f + __expf(-2.0f * x)) - 1.0f; }
__device__ __forceinline__ float lrelu_(float x)    { return x > 0.0f ? x : 0.01f * x; }

// ---------------------------------------------------------------------------
// Fused 2-layer LSTM. One block = R rows, persistent h/c state across T.
// Thread tid = gate index g (0..255). Whh0/Wih1/Whh1 rows live in registers
// (64 floats each = 192 VGPRs). h in LDS, c in per-thread registers.
// Only the final h of layer 1 is written out (downstream needs last step only).
// ---------------------------------------------------------------------------
constexpr int R = 8;

__global__ __launch_bounds__(256, 2)
void lstm_fused_kernel(const float* __restrict__ x,
                       const float* __restrict__ Wih0, const float* __restrict__ Whh0,
                       const float* __restrict__ bih0, const float* __restrict__ bhh0,
                       const float* __restrict__ Wih1, const float* __restrict__ Whh1,
                       const float* __restrict__ bih1, const float* __restrict__ bhh1,
                       float* __restrict__ last_out)
{
    __shared__ float sWih0[DF][GG];      // Wih0 transposed
    __shared__ float sb0[GG];
    __shared__ float sb1[GG];
    __shared__ float sx[R][TT][DF];      // this block's x, preloaded
    __shared__ float sh0[R][HH];
    __shared__ float sh1[R][HH];
    __shared__ float sg[R][GG];          // gate scratch

    const int tid = threadIdx.x;
    const int n0  = blockIdx.x * R;

    float w0[HH], wi1[HH], wh1[HH];
    {
        const float4* p0 = (const float4*)(Whh0 + (size_t)tid * HH);
        const float4* p1 = (const float4*)(Wih1 + (size_t)tid * HH);
        const float4* p2 = (const float4*)(Whh1 + (size_t)tid * HH);
        #pragma unroll
        for (int k = 0; k < HH / 4; k++) {
            float4 v0 = p0[k]; w0 [4*k]=v0.x; w0 [4*k+1]=v0.y; w0 [4*k+2]=v0.z; w0 [4*k+3]=v0.w;
            float4 v1 = p1[k]; wi1[4*k]=v1.x; wi1[4*k+1]=v1.y; wi1[4*k+2]=v1.z; wi1[4*k+3]=v1.w;
            float4 v2 = p2[k]; wh1[4*k]=v2.x; wh1[4*k+1]=v2.y; wh1[4*k+2]=v2.z; wh1[4*k+3]=v2.w;
        }
    }
    sb0[tid] = bih0[tid] + bhh0[tid];
    sb1[tid] = bih1[tid] + bhh1[tid];
    #pragma unroll
    for (int d = 0; d < DF; d++) sWih0[d][tid] = Wih0[tid * DF + d];
    {
        const float* xs = x + (size_t)n0 * TT * DF;
        float* dst = &sx[0][0][0];
        for (int idx = tid; idx < R * TT * DF; idx += 256) dst[idx] = xs[idx];
    }
    const int kl = tid & (HH - 1);
    const int rq = tid >> 6;            // 0..3 ; this thread owns rows rq, rq+4 in pointwise phase
    sh0[rq][kl] = 0.f; sh0[rq+4][kl] = 0.f;
    sh1[rq][kl] = 0.f; sh1[rq+4][kl] = 0.f;
    float c0a = 0.f, c0b = 0.f, c1a = 0.f, c1b = 0.f;
    __syncthreads();

    for (int t = 0; t < TT; t++) {
        float acc[R];
        // ---- layer 0 gates: xg + h0 @ Whh0^T ----
        #pragma unroll
        for (int r = 0; r < R; r++) acc[r] = sb0[tid];
        #pragma unroll
        for (int d = 0; d < DF; d++) {
            const float wv = sWih0[d][tid];
            #pragma unroll
            for (int r = 0; r < R; r++) acc[r] += wv * sx[r][t][d];
        }
        #pragma unroll
        for (int k4 = 0; k4 < HH; k4 += 4) {
            #pragma unroll
            for (int r = 0; r < R; r++) {
                const float4 h4 = *(const float4*)&sh0[r][k4];
                acc[r] += w0[k4]*h4.x + w0[k4+1]*h4.y + w0[k4+2]*h4.z + w0[k4+3]*h4.w;
            }
        }
        #pragma unroll
        for (int r = 0; r < R; r++) sg[r][tid] = acc[r];
        __syncthreads();
        // ---- layer 0 pointwise ----
        {
            float gi = sg[rq][kl], gf = sg[rq][HH+kl], gc = sg[rq][2*HH+kl], go = sg[rq][3*HH+kl];
            c0a = sigmoidf_(gf)*c0a + sigmoidf_(gi)*tanhf_(gc);
            sh0[rq][kl] = sigmoidf_(go)*tanhf_(c0a);
            gi = sg[rq+4][kl]; gf = sg[rq+4][HH+kl]; gc = sg[rq+4][2*HH+kl]; go = sg[rq+4][3*HH+kl];
            c0b = sigmoidf_(gf)*c0b + sigmoidf_(gi)*tanhf_(gc);
            sh0[rq+4][kl] = sigmoidf_(go)*tanhf_(c0b);
        }
        __syncthreads();
        // ---- layer 1 gates: h0 @ Wih1^T + h1 @ Whh1^T ----
        #pragma unroll
        for (int r = 0; r < R; r++) acc[r] = sb1[tid];
        #pragma unroll
        for (int k4 = 0; k4 < HH; k4 += 4) {
            #pragma unroll
            for (int r = 0; r < R; r++) {
                const float4 x4 = *(const float4*)&sh0[r][k4];
                acc[r] += wi1[k4]*x4.x + wi1[k4+1]*x4.y + wi1[k4+2]*x4.z + wi1[k4+3]*x4.w;
            }
        }
        #pragma unroll
        for (int k4 = 0; k4 < HH; k4 += 4) {
            #pragma unroll
            for (int r = 0; r < R; r++) {
                const float4 h4 = *(const float4*)&sh1[r][k4];
                acc[r] += wh1[k4]*h4.x + wh1[k4+1]*h4.y + wh1[k4+2]*h4.z + wh1[k4+3]*h4.w;
            }
        }
        #pragma unroll
        for (int r = 0; r < R; r++) sg[r][tid] = acc[r];
        __syncthreads();
        // ---- layer 1 pointwise ----
        {
            float gi = sg[rq][kl], gf = sg[rq][HH+kl], gc = sg[rq][2*HH+kl], go = sg[rq][3*HH+kl];
            c1a = sigmoidf_(gf)*c1a + sigmoidf_(gi)*tanhf_(gc);
            float h = sigmoidf_(go)*tanhf_(c1a);
            sh1[rq][kl] = h;
            if (t == TT-1) last_out[(size_t)(n0+rq)*HH + kl] = h;
            gi = sg[rq+4][kl]; gf = sg[rq+4][HH+kl]; gc = sg[rq+4][2*HH+kl]; go = sg[rq+4][3*HH+kl];
            c1b = sigmoidf_(gf)*c1b + sigmoidf_(gi)*tanhf_(gc);
            h = sigmoidf_(go)*tanhf_(c1b);
            sh1[rq+4][kl] = h;
            if (t == TT-1) last_out[(size_t)(n0+rq+4)*HH + kl] = h;
        }
        __syncthreads();
    }
}

// ---------------------------------------------------------------------------
// GAT prep: hgat = last @ Wt^T + bt ; s1 = hgat·a[:H] ; s2 = hgat·a[H:]
// + per-block max of s1.
// ---------------------------------------------------------------------------
__global__ void gat_prep_kernel(const float* __restrict__ last,
                                const float* __restrict__ Wt, const float* __restrict__ bt,
                                const float* __restrict__ a,
                                float* __restrict__ s1, float* __restrict__ s2,
                                float* __restrict__ blkmax)
{
    __shared__ float sWtT[HH][HH + 1];
    __shared__ float slast[16][HH];
    __shared__ float sbt[HH], sa1[HH], sa2[HH];
    __shared__ float swm[4];
    const int tid = threadIdx.x;
    for (int idx = tid; idx < HH * HH; idx += 256) {
        const int h = idx >> 6, d = idx & 63;
        sWtT[d][h] = Wt[idx];
    }
    if (tid < HH) { sbt[tid] = bt[tid]; sa1[tid] = a[tid]; sa2[tid] = a[HH + tid]; }
    const int n0 = blockIdx.x * 16;
    for (int idx = tid; idx < 16 * HH; idx += 256)
        (&slast[0][0])[idx] = last[(size_t)n0 * HH + idx];
    __syncthreads();
    const int w = tid >> 6, l = tid & 63;
    float wmax = -1e30f;
    for (int rr = 0; rr < 4; rr++) {
        const int r = w * 4 + rr;
        float acc = sbt[l];
        #pragma unroll
        for (int d = 0; d < HH; d++) acc += slast[r][d] * sWtT[d][l];
        float p1 = acc * sa1[l], p2 = acc * sa2[l];
        #pragma unroll
        for (int off = 32; off > 0; off >>= 1) {
            p1 += __shfl_xor(p1, off);
            p2 += __shfl_xor(p2, off);
        }
        if (l == 0) { s1[n0 + r] = p1; s2[n0 + r] = p2; }
        wmax = fmaxf(wmax, p1);
    }
    if (l == 0) swm[w] = wmax;
    __syncthreads();
    if (tid == 0) blkmax[blockIdx.x] = fmaxf(fmaxf(swm[0], swm[1]), fmaxf(swm[2], swm[3]));
}

// ---------------------------------------------------------------------------
// Finalize: global s1max; per-node factors for the exact separable softmax:
//   m_i = lr(z_i), z_i = s2_i + s1max
//   P_ij = (z_i + d_j > 0) ? a_i*u_j : b_i*w_j,  all factors <= 1.
// ---------------------------------------------------------------------------
__global__ void gat_finalize_kernel(const float* __restrict__ s1, const float* __restrict__ s2,
                                    const float* __restrict__ blkmax,
                                    float* __restrict__ Z, float* __restrict__ Ai, float* __restrict__ Bi,
                                    float* __restrict__ Dj, float* __restrict__ Uj, float* __restrict__ Wj)
{
    __shared__ float red[256];
    const int tid = threadIdx.x;
    red[tid] = fmaxf(blkmax[tid], blkmax[tid + 256]);
    __syncthreads();
    for (int s = 128; s > 0; s >>= 1) {
        if (tid < s) red[tid] = fmaxf(red[tid], red[tid + s]);
        __syncthreads();
    }
    const float s1max = red[0];
    for (int i = tid; i < NN; i += 256) {
        const float z  = s2[i] + s1max;
        const float mi = lrelu_(z);
        Z[i]  = z;
        Ai[i] = __expf(z - mi);
        Bi[i] = __expf(0.01f * z - mi);
        const float d = s1[i] - s1max;
        Dj[i] = d;
        Uj[i] = __expf(d);
        Wj[i] = __expf(0.01f * d);
    }
}

// ---------------------------------------------------------------------------
// Attention: out[i] = (sum_j P_ij * last[j]) / (sum_j P_ij) + last[i]
// Block = 32 i's; thread (il, half) accumulates dims half*8..half*8+7.
// ---------------------------------------------------------------------------
__global__ __launch_bounds__(256)
void gat_attn_kernel(const float* __restrict__ last,
                     const float* __restrict__ Z, const float* __restrict__ Ai, const float* __restrict__ Bi,
                     const float* __restrict__ Dj, const float* __restrict__ Uj, const float* __restrict__ Wj,
                     float* __restrict__ gout)
{
    __shared__ float sl[128][HH];
    __shared__ float sd[128], su[128], sw[128];
    const int tid  = threadIdx.x;
    const int il   = tid & 31, half = tid >> 5;
    const int i    = blockIdx.x * 32 + il;
    const float zi = Z[i], ai = Ai[i], bi = Bi[i];
    float acc[8] = {0,0,0,0,0,0,0,0};
    float den = 0.f;
    for (int j0 = 0; j0 < NN; j0 += 128) {
        for (int idx = tid; idx < 128 * HH / 4; idx += 256)
            ((float4*)&sl[0][0])[idx] = ((const float4*)(last + (size_t)j0 * HH))[idx];
        if (tid < 128) { sd[tid] = Dj[j0+tid]; su[tid] = Uj[j0+tid]; sw[tid] = Wj[j0+tid]; }
        __syncthreads();
        #pragma unroll 4
        for (int jj = 0; jj < 128; jj++) {
            const float p = (zi + sd[jj] > 0.f) ? ai * su[jj] : bi * sw[jj];
            den += p;
            const float* lj = &sl[jj][half * 8];
            #pragma unroll
            for (int q = 0; q < 8; q++) acc[q] += p * lj[q];
        }
        __syncthreads();
    }
    const float inv = 1.f / den;
    const size_t base = (size_t)i * HH + half * 8;
    #pragma unroll
    for (int q = 0; q < 8; q++) gout[base + q] = acc[q] * inv + last[base + q];
}

// ---------------------------------------------------------------------------
// hidden = lrelu(gout @ Wfc^T + bfc); out = hidden @ Wout^T + bout
// ---------------------------------------------------------------------------
__global__ void fc_out_kernel(const float* __restrict__ gout,
                              const float* __restrict__ Wfc, const float* __restrict__ bfc,
                              const float* __restrict__ Wout, const float* __restrict__ bout,
                              float* __restrict__ out)
{
    __shared__ float sW[HH][HH + 1];
    __shared__ float sb[HH], sa[HH];
    const int tid = threadIdx.x;
    for (int idx = tid; idx < HH * HH; idx += 256) {
        const int h = idx >> 6, d = idx & 63;
        sW[d][h] = Wfc[idx];
    }
    if (tid < HH) { sb[tid] = bfc[tid]; sa[tid] = Wout[tid]; }
    __syncthreads();
    const int w = tid >> 6, l = tid & 63;
    const float bo = bout[0];
    int n = blockIdx.x * 8 + w * 2;
    for (int rep = 0; rep < 2; rep++, n++) {
        const float vl = gout[(size_t)n * HH + l];
        float acc = sb[l];
        #pragma unroll
        for (int d = 0; d < HH; d++) acc += __shfl(vl, d) * sW[d][l];
        float prod = lrelu_(acc) * sa[l];
        #pragma unroll
        for (int off = 32; off > 0; off >>= 1) prod += __shfl_xor(prod, off);
        if (l == 0) out[n] = prod + bo;
    }
}

extern "C" void kernel_launch(void* const* d_in, const int* in_sizes, int n_in,
                              void* d_out, int out_size, void* d_ws, size_t ws_size,
                              hipStream_t stream)
{
    (void)in_sizes; (void)n_in; (void)out_size; (void)ws_size;
    const float* x    = (const float*)d_in[0];
    const float* Wih0 = (const float*)d_in[1];
    const float* Whh0 = (const float*)d_in[2];
    const float* bih0 = (const float*)d_in[3];
    const float* bhh0 = (const float*)d_in[4];
    const float* Wih1 = (const float*)d_in[5];
    const float* Whh1 = (const float*)d_in[6];
    const float* bih1 = (const float*)d_in[7];
    const float* bhh1 = (const float*)d_in[8];
    const float* Wt   = (const float*)d_in[9];
    const float* bt   = (const float*)d_in[10];
    const float* a    = (const float*)d_in[11];
    const float* Wfc  = (const float*)d_in[12];
    const float* bfc  = (const float*)d_in[13];
    const float* Wout = (const float*)d_in[14];
    const float* bout = (const float*)d_in[15];
    float* out = (float*)d_out;

    float* ws     = (float*)d_ws;
    float* last   = ws;                    // N*H
    float* gout   = last + (size_t)NN*HH;  // N*H
    float* s1     = gout + (size_t)NN*HH;  // N
    float* s2     = s1 + NN;
    float* Z      = s2 + NN;
    float* Ai     = Z + NN;
    float* Bi     = Ai + NN;
    float* Dj     = Bi + NN;
    float* Uj     = Dj + NN;
    float* Wj     = Uj + NN;
    float* blkmax = Wj + NN;               // 512

    lstm_fused_kernel<<<dim3(NN / R), dim3(256), 0, stream>>>(
        x, Wih0, Whh0, bih0, bhh0, Wih1, Whh1, bih1, bhh1, last);
    gat_prep_kernel<<<dim3(NN / 16), dim3(256), 0, stream>>>(
        last, Wt, bt, a, s1, s2, blkmax);
    gat_finalize_kernel<<<dim3(1), dim3(256), 0, stream>>>(
        s1, s2, blkmax, Z, Ai, Bi, Dj, Uj, Wj);
    gat_attn_kernel<<<dim3(NN / 32), dim3(256), 0, stream>>>(
        last, Z, Ai, Bi, Dj, Uj, Wj, gout);
    fc_out_kernel<<<dim3(NN / 8), dim3(256), 0, stream>>>(
        gout, Wfc, bfc, Wout, bout, out);
}

// Round 2
// 761.696 us; speedup vs baseline: 3.2172x; 3.2172x over previous
//
#include <hip/hip_runtime.h>

#define NN 8192
#define TT 60
#define DF 6
#define HH 64
#define GG 256   // 4*H

typedef _Float16 half8 __attribute__((ext_vector_type(8)));
typedef float f32x4 __attribute__((ext_vector_type(4)));
#define MFMA16(a, b, c) __builtin_amdgcn_mfma_f32_16x16x32_f16((a), (b), (c), 0, 0, 0)

__device__ __forceinline__ float sigmoidf_(float x) { return 1.0f / (1.0f + __expf(-x)); }
__device__ __forceinline__ float tanhf_(float x)    { return 2.0f / (1.0f + __expf(-2.0f * x)) - 1.0f; }
__device__ __forceinline__ float lrelu_(float x)    { return x > 0.0f ? x : 0.01f * x; }

__device__ __forceinline__ half8 ldw8(const float* __restrict__ p) {
    const float4* q = (const float4*)p;
    float4 u = q[0], v = q[1];
    half8 r;
    r[0]=(_Float16)u.x; r[1]=(_Float16)u.y; r[2]=(_Float16)u.z; r[3]=(_Float16)u.w;
    r[4]=(_Float16)v.x; r[5]=(_Float16)v.y; r[6]=(_Float16)v.z; r[7]=(_Float16)v.w;
    return r;
}

// ---------------------------------------------------------------------------
// MFMA 2-layer LSTM. Block = 16 sequence rows (M=16), 4 waves.
// Wave w owns gate columns {nt*64 + w*16 + (lane&15)} for nt in {i,f,g,o} ->
// all 4 gate values of one (row, h-col) sit in the same lane across 4 D-frags,
// so the pointwise runs in registers and c-state is persistent VGPR.
// h crosses steps through double-buffered fp16 LDS (2 barriers/step).
// Weights live in fp16 B-frag registers (loaded once). K=6 input projection is
// a zero-padded K=32 MFMA. All accumulation fp32.
// ---------------------------------------------------------------------------
#define SXW (TT * 8 + 8)   // padded x row stride (halves); +8 breaks LDS bank aliasing

__global__ __launch_bounds__(256, 2)
void lstm_fused_kernel(const float* __restrict__ x,
                       const float* __restrict__ Wih0, const float* __restrict__ Whh0,
                       const float* __restrict__ bih0, const float* __restrict__ bhh0,
                       const float* __restrict__ Wih1, const float* __restrict__ Whh1,
                       const float* __restrict__ bih1, const float* __restrict__ bhh1,
                       float* __restrict__ last_out)
{
    __shared__ _Float16 sxp[16][SXW];        // x in fp16, 8-slot per t (6 data + 2 zero)
    __shared__ _Float16 h0buf[2][16][72];    // 72 = 64 + 8 pad (conflict break), 16B-aligned rows
    __shared__ _Float16 h1buf[2][16][72];
    __shared__ _Float16 zero16[8];

    const int tid  = threadIdx.x;
    const int w    = tid >> 6;
    const int lane = tid & 63;
    const int quad = lane >> 4;
    const int l15  = lane & 15;
    const int hc   = w * 16 + l15;           // this lane's h-column (pointwise/B-col role)
    const int n0   = blockIdx.x * 16;

    // ---- zero LDS (x pad slots + h parity buffers) ----
    for (int i = tid; i < 16 * SXW / 2; i += 256) ((unsigned*)sxp)[i] = 0u;
    for (int i = tid; i < 2 * 16 * 72 / 2; i += 256) ((unsigned*)h0buf)[i] = 0u;
    for (int i = tid; i < 2 * 16 * 72 / 2; i += 256) ((unsigned*)h1buf)[i] = 0u;
    if (tid < 4) ((unsigned*)zero16)[tid] = 0u;
    __syncthreads();

    // ---- stage x -> fp16 LDS ----
    for (int idx = tid; idx < 16 * TT * DF; idx += 256) {
        const int m = idx / (TT * DF);
        const int r = idx - m * (TT * DF);
        const int t = r / DF;
        const int d = r - t * DF;
        sxp[m][t * 8 + d] = (_Float16)x[(size_t)(n0 + m) * (TT * DF) + r];
    }

    // ---- weight fragments (fp16, registers) ----
    half8 bhh0f[4][2], bih1f[4][2], bhh1f[4][2], bxf[4];
    float bias0[4], bias1[4];
    #pragma unroll
    for (int nt = 0; nt < 4; nt++) {
        const int g = nt * 64 + hc;
        #pragma unroll
        for (int kc = 0; kc < 2; kc++) {
            const int k0 = kc * 32 + quad * 8;
            bhh0f[nt][kc] = ldw8(Whh0 + (size_t)g * HH + k0);
            bih1f[nt][kc] = ldw8(Wih1 + (size_t)g * HH + k0);
            bhh1f[nt][kc] = ldw8(Whh1 + (size_t)g * HH + k0);
        }
        bias0[nt] = bih0[g] + bhh0[g];
        bias1[nt] = bih1[g] + bhh1[g];
        half8 t;
        #pragma unroll
        for (int j = 0; j < 8; j++) t[j] = (_Float16)0.f;
        if (quad == 0) {
            #pragma unroll
            for (int j = 0; j < DF; j++) t[j] = (_Float16)Wih0[g * DF + j];
        }
        bxf[nt] = t;
    }

    float c0[4] = {0.f, 0.f, 0.f, 0.f};
    float c1[4] = {0.f, 0.f, 0.f, 0.f};
    __syncthreads();

    int p = 0;
    for (int t = 0; t < TT; t++) {
        // A-frags for h0_{t-1}, h1_{t-1} (buf p)
        const half8 a_h0_0 = *(const half8*)&h0buf[p][l15][quad * 8];
        const half8 a_h0_1 = *(const half8*)&h0buf[p][l15][32 + quad * 8];
        const half8 a_h1_0 = *(const half8*)&h1buf[p][l15][quad * 8];
        const half8 a_h1_1 = *(const half8*)&h1buf[p][l15][32 + quad * 8];
        const _Float16* xap = (quad == 0) ? &sxp[l15][t * 8] : zero16;
        const half8 ax = *(const half8*)xap;

        // ---- layer 0 gates ----
        f32x4 g0v[4];
        #pragma unroll
        for (int nt = 0; nt < 4; nt++) {
            f32x4 c; c[0] = bias0[nt]; c[1] = bias0[nt]; c[2] = bias0[nt]; c[3] = bias0[nt];
            c = MFMA16(ax, bxf[nt], c);
            c = MFMA16(a_h0_0, bhh0f[nt][0], c);
            c = MFMA16(a_h0_1, bhh0f[nt][1], c);
            g0v[nt] = c;
        }
        // ---- layer 0 pointwise (rows quad*4+reg, col hc) ----
        _Float16 (*h0w)[72] = h0buf[p ^ 1];
        #pragma unroll
        for (int reg = 0; reg < 4; reg++) {
            const float gi = g0v[0][reg], gf = g0v[1][reg], gc = g0v[2][reg], go = g0v[3][reg];
            const float cc = sigmoidf_(gf) * c0[reg] + sigmoidf_(gi) * tanhf_(gc);
            c0[reg] = cc;
            h0w[quad * 4 + reg][hc] = (_Float16)(sigmoidf_(go) * tanhf_(cc));
        }
        __syncthreads();

        // ---- layer 1 gates ----
        const half8 a_h0n_0 = *(const half8*)&h0buf[p ^ 1][l15][quad * 8];
        const half8 a_h0n_1 = *(const half8*)&h0buf[p ^ 1][l15][32 + quad * 8];
        f32x4 g1v[4];
        #pragma unroll
        for (int nt = 0; nt < 4; nt++) {
            f32x4 c; c[0] = bias1[nt]; c[1] = bias1[nt]; c[2] = bias1[nt]; c[3] = bias1[nt];
            c = MFMA16(a_h0n_0, bih1f[nt][0], c);
            c = MFMA16(a_h0n_1, bih1f[nt][1], c);
            c = MFMA16(a_h1_0, bhh1f[nt][0], c);
            c = MFMA16(a_h1_1, bhh1f[nt][1], c);
            g1v[nt] = c;
        }
        // ---- layer 1 pointwise ----
        _Float16 (*h1w)[72] = h1buf[p ^ 1];
        #pragma unroll
        for (int reg = 0; reg < 4; reg++) {
            const float gi = g1v[0][reg], gf = g1v[1][reg], gc = g1v[2][reg], go = g1v[3][reg];
            const float cc = sigmoidf_(gf) * c1[reg] + sigmoidf_(gi) * tanhf_(gc);
            c1[reg] = cc;
            const float hv = sigmoidf_(go) * tanhf_(cc);
            h1w[quad * 4 + reg][hc] = (_Float16)hv;
            if (t == TT - 1) last_out[(size_t)(n0 + quad * 4 + reg) * HH + hc] = hv;
        }
        __syncthreads();
        p ^= 1;
    }
}

// ---------------------------------------------------------------------------
// GAT prep: hgat = last @ Wt^T + bt ; s1 = hgat·a[:H] ; s2 = hgat·a[H:]
// + per-block max of s1.
// ---------------------------------------------------------------------------
__global__ void gat_prep_kernel(const float* __restrict__ last,
                                const float* __restrict__ Wt, const float* __restrict__ bt,
                                const float* __restrict__ a,
                                float* __restrict__ s1, float* __restrict__ s2,
                                float* __restrict__ blkmax)
{
    __shared__ float sWtT[HH][HH + 1];
    __shared__ float slast[16][HH];
    __shared__ float sbt[HH], sa1[HH], sa2[HH];
    __shared__ float swm[4];
    const int tid = threadIdx.x;
    for (int idx = tid; idx < HH * HH; idx += 256) {
        const int h = idx >> 6, d = idx & 63;
        sWtT[d][h] = Wt[idx];
    }
    if (tid < HH) { sbt[tid] = bt[tid]; sa1[tid] = a[tid]; sa2[tid] = a[HH + tid]; }
    const int n0 = blockIdx.x * 16;
    for (int idx = tid; idx < 16 * HH; idx += 256)
        (&slast[0][0])[idx] = last[(size_t)n0 * HH + idx];
    __syncthreads();
    const int w = tid >> 6, l = tid & 63;
    float wmax = -1e30f;
    for (int rr = 0; rr < 4; rr++) {
        const int r = w * 4 + rr;
        float acc = sbt[l];
        #pragma unroll
        for (int d = 0; d < HH; d++) acc += slast[r][d] * sWtT[d][l];
        float p1 = acc * sa1[l], p2 = acc * sa2[l];
        #pragma unroll
        for (int off = 32; off > 0; off >>= 1) {
            p1 += __shfl_xor(p1, off);
            p2 += __shfl_xor(p2, off);
        }
        if (l == 0) { s1[n0 + r] = p1; s2[n0 + r] = p2; }
        wmax = fmaxf(wmax, p1);
    }
    if (l == 0) swm[w] = wmax;
    __syncthreads();
    if (tid == 0) blkmax[blockIdx.x] = fmaxf(fmaxf(swm[0], swm[1]), fmaxf(swm[2], swm[3]));
}

// ---------------------------------------------------------------------------
// Finalize: global s1max; per-node factors for the exact separable softmax:
//   m_i = lr(z_i), z_i = s2_i + s1max
//   P_ij = (z_i + d_j > 0) ? a_i*u_j : b_i*w_j,  all factors <= 1.
// ---------------------------------------------------------------------------
__global__ void gat_finalize_kernel(const float* __restrict__ s1, const float* __restrict__ s2,
                                    const float* __restrict__ blkmax,
                                    float* __restrict__ Z, float* __restrict__ Ai, float* __restrict__ Bi,
                                    float* __restrict__ Dj, float* __restrict__ Uj, float* __restrict__ Wj)
{
    __shared__ float red[256];
    const int tid = threadIdx.x;
    red[tid] = fmaxf(blkmax[tid], blkmax[tid + 256]);
    __syncthreads();
    for (int s = 128; s > 0; s >>= 1) {
        if (tid < s) red[tid] = fmaxf(red[tid], red[tid + s]);
        __syncthreads();
    }
    const float s1max = red[0];
    for (int i = tid; i < NN; i += 256) {
        const float z  = s2[i] + s1max;
        const float mi = lrelu_(z);
        Z[i]  = z;
        Ai[i] = __expf(z - mi);
        Bi[i] = __expf(0.01f * z - mi);
        const float d = s1[i] - s1max;
        Dj[i] = d;
        Uj[i] = __expf(d);
        Wj[i] = __expf(0.01f * d);
    }
}

// ---------------------------------------------------------------------------
// Attention: out[i] = (sum_j P_ij * last[j]) / (sum_j P_ij) + last[i]
// Block = 32 i's; thread (il, half) accumulates dims half*8..half*8+7.
// ---------------------------------------------------------------------------
__global__ __launch_bounds__(256)
void gat_attn_kernel(const float* __restrict__ last,
                     const float* __restrict__ Z, const float* __restrict__ Ai, const float* __restrict__ Bi,
                     const float* __restrict__ Dj, const float* __restrict__ Uj, const float* __restrict__ Wj,
                     float* __restrict__ gout)
{
    __shared__ float sl[128][HH];
    __shared__ float sd[128], su[128], sw[128];
    const int tid  = threadIdx.x;
    const int il   = tid & 31, half = tid >> 5;
    const int i    = blockIdx.x * 32 + il;
    const float zi = Z[i], ai = Ai[i], bi = Bi[i];
    float acc[8] = {0,0,0,0,0,0,0,0};
    float den = 0.f;
    for (int j0 = 0; j0 < NN; j0 += 128) {
        for (int idx = tid; idx < 128 * HH / 4; idx += 256)
            ((float4*)&sl[0][0])[idx] = ((const float4*)(last + (size_t)j0 * HH))[idx];
        if (tid < 128) { sd[tid] = Dj[j0+tid]; su[tid] = Uj[j0+tid]; sw[tid] = Wj[j0+tid]; }
        __syncthreads();
        #pragma unroll 4
        for (int jj = 0; jj < 128; jj++) {
            const float p = (zi + sd[jj] > 0.f) ? ai * su[jj] : bi * sw[jj];
            den += p;
            const float* lj = &sl[jj][half * 8];
            #pragma unroll
            for (int q = 0; q < 8; q++) acc[q] += p * lj[q];
        }
        __syncthreads();
    }
    const float inv = 1.f / den;
    const size_t base = (size_t)i * HH + half * 8;
    #pragma unroll
    for (int q = 0; q < 8; q++) gout[base + q] = acc[q] * inv + last[base + q];
}

// ---------------------------------------------------------------------------
// hidden = lrelu(gout @ Wfc^T + bfc); out = hidden @ Wout^T + bout
// ---------------------------------------------------------------------------
__global__ void fc_out_kernel(const float* __restrict__ gout,
                              const float* __restrict__ Wfc, const float* __restrict__ bfc,
                              const float* __restrict__ Wout, const float* __restrict__ bout,
                              float* __restrict__ out)
{
    __shared__ float sW[HH][HH + 1];
    __shared__ float sb[HH], sa[HH];
    const int tid = threadIdx.x;
    for (int idx = tid; idx < HH * HH; idx += 256) {
        const int h = idx >> 6, d = idx & 63;
        sW[d][h] = Wfc[idx];
    }
    if (tid < HH) { sb[tid] = bfc[tid]; sa[tid] = Wout[tid]; }
    __syncthreads();
    const int w = tid >> 6, l = tid & 63;
    const float bo = bout[0];
    int n = blockIdx.x * 8 + w * 2;
    for (int rep = 0; rep < 2; rep++, n++) {
        const float vl = gout[(size_t)n * HH + l];
        float acc = sb[l];
        #pragma unroll
        for (int d = 0; d < HH; d++) acc += __shfl(vl, d) * sW[d][l];
        float prod = lrelu_(acc) * sa[l];
        #pragma unroll
        for (int off = 32; off > 0; off >>= 1) prod += __shfl_xor(prod, off);
        if (l == 0) out[n] = prod + bo;
    }
}

extern "C" void kernel_launch(void* const* d_in, const int* in_sizes, int n_in,
                              void* d_out, int out_size, void* d_ws, size_t ws_size,
                              hipStream_t stream)
{
    (void)in_sizes; (void)n_in; (void)out_size; (void)ws_size;
    const float* x    = (const float*)d_in[0];
    const float* Wih0 = (const float*)d_in[1];
    const float* Whh0 = (const float*)d_in[2];
    const float* bih0 = (const float*)d_in[3];
    const float* bhh0 = (const float*)d_in[4];
    const float* Wih1 = (const float*)d_in[5];
    const float* Whh1 = (const float*)d_in[6];
    const float* bih1 = (const float*)d_in[7];
    const float* bhh1 = (const float*)d_in[8];
    const float* Wt   = (const float*)d_in[9];
    const float* bt   = (const float*)d_in[10];
    const float* a    = (const float*)d_in[11];
    const float* Wfc  = (const float*)d_in[12];
    const float* bfc  = (const float*)d_in[13];
    const float* Wout = (const float*)d_in[14];
    const float* bout = (const float*)d_in[15];
    float* out = (float*)d_out;

    float* ws     = (float*)d_ws;
    float* last   = ws;                    // N*H
    float* gout   = last + (size_t)NN*HH;  // N*H
    float* s1     = gout + (size_t)NN*HH;  // N
    float* s2     = s1 + NN;
    float* Z      = s2 + NN;
    float* Ai     = Z + NN;
    float* Bi     = Ai + NN;
    float* Dj     = Bi + NN;
    float* Uj     = Dj + NN;
    float* Wj     = Uj + NN;
    float* blkmax = Wj + NN;               // 512

    lstm_fused_kernel<<<dim3(NN / 16), dim3(256), 0, stream>>>(
        x, Wih0, Whh0, bih0, bhh0, Wih1, Whh1, bih1, bhh1, last);
    gat_prep_kernel<<<dim3(NN / 16), dim3(256), 0, stream>>>(
        last, Wt, bt, a, s1, s2, blkmax);
    gat_finalize_kernel<<<dim3(1), dim3(256), 0, stream>>>(
        s1, s2, blkmax, Z, Ai, Bi, Dj, Uj, Wj);
    gat_attn_kernel<<<dim3(NN / 32), dim3(256), 0, stream>>>(
        last, Z, Ai, Bi, Dj, Uj, Wj, gout);
    fc_out_kernel<<<dim3(NN / 8), dim3(256), 0, stream>>>(
        gout, Wfc, bfc, Wout, bout, out);
}

// Round 3
// 387.759 us; speedup vs baseline: 6.3196x; 1.9644x over previous
//
#include <hip/hip_runtime.h>

#define NN 8192
#define TT 60
#define DF 6
#define HH 64
#define GG 256   // 4*H
#define RS 132   // sorted-row stride: [0..63] u*last, [64..127] w*last, [128] u, [129] w

typedef _Float16 half8 __attribute__((ext_vector_type(8)));
typedef float f32x4 __attribute__((ext_vector_type(4)));
#define MFMA16(a, b, c) __builtin_amdgcn_mfma_f32_16x16x32_f16((a), (b), (c), 0, 0, 0)

__device__ __forceinline__ float sigmoidf_(float x) { return 1.0f / (1.0f + __expf(-x)); }
__device__ __forceinline__ float tanhf_(float x)    { return 2.0f / (1.0f + __expf(-2.0f * x)) - 1.0f; }
__device__ __forceinline__ float lrelu_(float x)    { return x > 0.0f ? x : 0.01f * x; }

__device__ __forceinline__ half8 ldw8(const float* __restrict__ p) {
    const float4* q = (const float4*)p;
    float4 u = q[0], v = q[1];
    half8 r;
    r[0]=(_Float16)u.x; r[1]=(_Float16)u.y; r[2]=(_Float16)u.z; r[3]=(_Float16)u.w;
    r[4]=(_Float16)v.x; r[5]=(_Float16)v.y; r[6]=(_Float16)v.z; r[7]=(_Float16)v.w;
    return r;
}

// ---------------------------------------------------------------------------
// MFMA 2-layer LSTM (unchanged from R2). Block = 16 rows, 4 waves.
// ---------------------------------------------------------------------------
#define SXW (TT * 8 + 8)

__global__ __launch_bounds__(256, 2)
void lstm_fused_kernel(const float* __restrict__ x,
                       const float* __restrict__ Wih0, const float* __restrict__ Whh0,
                       const float* __restrict__ bih0, const float* __restrict__ bhh0,
                       const float* __restrict__ Wih1, const float* __restrict__ Whh1,
                       const float* __restrict__ bih1, const float* __restrict__ bhh1,
                       float* __restrict__ last_out)
{
    __shared__ _Float16 sxp[16][SXW];
    __shared__ _Float16 h0buf[2][16][72];
    __shared__ _Float16 h1buf[2][16][72];
    __shared__ _Float16 zero16[8];

    const int tid  = threadIdx.x;
    const int w    = tid >> 6;
    const int lane = tid & 63;
    const int quad = lane >> 4;
    const int l15  = lane & 15;
    const int hc   = w * 16 + l15;
    const int n0   = blockIdx.x * 16;

    for (int i = tid; i < 16 * SXW / 2; i += 256) ((unsigned*)sxp)[i] = 0u;
    for (int i = tid; i < 2 * 16 * 72 / 2; i += 256) ((unsigned*)h0buf)[i] = 0u;
    for (int i = tid; i < 2 * 16 * 72 / 2; i += 256) ((unsigned*)h1buf)[i] = 0u;
    if (tid < 4) ((unsigned*)zero16)[tid] = 0u;
    __syncthreads();

    for (int idx = tid; idx < 16 * TT * DF; idx += 256) {
        const int m = idx / (TT * DF);
        const int r = idx - m * (TT * DF);
        const int t = r / DF;
        const int d = r - t * DF;
        sxp[m][t * 8 + d] = (_Float16)x[(size_t)(n0 + m) * (TT * DF) + r];
    }

    half8 bhh0f[4][2], bih1f[4][2], bhh1f[4][2], bxf[4];
    float bias0[4], bias1[4];
    #pragma unroll
    for (int nt = 0; nt < 4; nt++) {
        const int g = nt * 64 + hc;
        #pragma unroll
        for (int kc = 0; kc < 2; kc++) {
            const int k0 = kc * 32 + quad * 8;
            bhh0f[nt][kc] = ldw8(Whh0 + (size_t)g * HH + k0);
            bih1f[nt][kc] = ldw8(Wih1 + (size_t)g * HH + k0);
            bhh1f[nt][kc] = ldw8(Whh1 + (size_t)g * HH + k0);
        }
        bias0[nt] = bih0[g] + bhh0[g];
        bias1[nt] = bih1[g] + bhh1[g];
        half8 t;
        #pragma unroll
        for (int j = 0; j < 8; j++) t[j] = (_Float16)0.f;
        if (quad == 0) {
            #pragma unroll
            for (int j = 0; j < DF; j++) t[j] = (_Float16)Wih0[g * DF + j];
        }
        bxf[nt] = t;
    }

    float c0[4] = {0.f, 0.f, 0.f, 0.f};
    float c1[4] = {0.f, 0.f, 0.f, 0.f};
    __syncthreads();

    int p = 0;
    for (int t = 0; t < TT; t++) {
        const half8 a_h0_0 = *(const half8*)&h0buf[p][l15][quad * 8];
        const half8 a_h0_1 = *(const half8*)&h0buf[p][l15][32 + quad * 8];
        const half8 a_h1_0 = *(const half8*)&h1buf[p][l15][quad * 8];
        const half8 a_h1_1 = *(const half8*)&h1buf[p][l15][32 + quad * 8];
        const _Float16* xap = (quad == 0) ? &sxp[l15][t * 8] : zero16;
        const half8 ax = *(const half8*)xap;

        f32x4 g0v[4];
        #pragma unroll
        for (int nt = 0; nt < 4; nt++) {
            f32x4 c; c[0] = bias0[nt]; c[1] = bias0[nt]; c[2] = bias0[nt]; c[3] = bias0[nt];
            c = MFMA16(ax, bxf[nt], c);
            c = MFMA16(a_h0_0, bhh0f[nt][0], c);
            c = MFMA16(a_h0_1, bhh0f[nt][1], c);
            g0v[nt] = c;
        }
        _Float16 (*h0w)[72] = h0buf[p ^ 1];
        #pragma unroll
        for (int reg = 0; reg < 4; reg++) {
            const float gi = g0v[0][reg], gf = g0v[1][reg], gc = g0v[2][reg], go = g0v[3][reg];
            const float cc = sigmoidf_(gf) * c0[reg] + sigmoidf_(gi) * tanhf_(gc);
            c0[reg] = cc;
            h0w[quad * 4 + reg][hc] = (_Float16)(sigmoidf_(go) * tanhf_(cc));
        }
        __syncthreads();

        const half8 a_h0n_0 = *(const half8*)&h0buf[p ^ 1][l15][quad * 8];
        const half8 a_h0n_1 = *(const half8*)&h0buf[p ^ 1][l15][32 + quad * 8];
        f32x4 g1v[4];
        #pragma unroll
        for (int nt = 0; nt < 4; nt++) {
            f32x4 c; c[0] = bias1[nt]; c[1] = bias1[nt]; c[2] = bias1[nt]; c[3] = bias1[nt];
            c = MFMA16(a_h0n_0, bih1f[nt][0], c);
            c = MFMA16(a_h0n_1, bih1f[nt][1], c);
            c = MFMA16(a_h1_0, bhh1f[nt][0], c);
            c = MFMA16(a_h1_1, bhh1f[nt][1], c);
            g1v[nt] = c;
        }
        _Float16 (*h1w)[72] = h1buf[p ^ 1];
        #pragma unroll
        for (int reg = 0; reg < 4; reg++) {
            const float gi = g1v[0][reg], gf = g1v[1][reg], gc = g1v[2][reg], go = g1v[3][reg];
            const float cc = sigmoidf_(gf) * c1[reg] + sigmoidf_(gi) * tanhf_(gc);
            c1[reg] = cc;
            const float hv = sigmoidf_(go) * tanhf_(cc);
            h1w[quad * 4 + reg][hc] = (_Float16)hv;
            if (t == TT - 1) last_out[(size_t)(n0 + quad * 4 + reg) * HH + hc] = hv;
        }
        __syncthreads();
        p ^= 1;
    }
}

// ---------------------------------------------------------------------------
// GAT prep (unchanged): s1, s2, per-block max of s1.
// ---------------------------------------------------------------------------
__global__ void gat_prep_kernel(const float* __restrict__ last,
                                const float* __restrict__ Wt, const float* __restrict__ bt,
                                const float* __restrict__ a,
                                float* __restrict__ s1, float* __restrict__ s2,
                                float* __restrict__ blkmax)
{
    __shared__ float sWtT[HH][HH + 1];
    __shared__ float slast[16][HH];
    __shared__ float sbt[HH], sa1[HH], sa2[HH];
    __shared__ float swm[4];
    const int tid = threadIdx.x;
    for (int idx = tid; idx < HH * HH; idx += 256) {
        const int h = idx >> 6, d = idx & 63;
        sWtT[d][h] = Wt[idx];
    }
    if (tid < HH) { sbt[tid] = bt[tid]; sa1[tid] = a[tid]; sa2[tid] = a[HH + tid]; }
    const int n0 = blockIdx.x * 16;
    for (int idx = tid; idx < 16 * HH; idx += 256)
        (&slast[0][0])[idx] = last[(size_t)n0 * HH + idx];
    __syncthreads();
    const int w = tid >> 6, l = tid & 63;
    float wmax = -1e30f;
    for (int rr = 0; rr < 4; rr++) {
        const int r = w * 4 + rr;
        float acc = sbt[l];
        #pragma unroll
        for (int d = 0; d < HH; d++) acc += slast[r][d] * sWtT[d][l];
        float p1 = acc * sa1[l], p2 = acc * sa2[l];
        #pragma unroll
        for (int off = 32; off > 0; off >>= 1) {
            p1 += __shfl_xor(p1, off);
            p2 += __shfl_xor(p2, off);
        }
        if (l == 0) { s1[n0 + r] = p1; s2[n0 + r] = p2; }
        wmax = fmaxf(wmax, p1);
    }
    if (l == 0) swm[w] = wmax;
    __syncthreads();
    if (tid == 0) blkmax[blockIdx.x] = fmaxf(fmaxf(swm[0], swm[1]), fmaxf(swm[2], swm[3]));
}

// ---------------------------------------------------------------------------
// Finalize: s1max; per-node separable-softmax factors; zero the rank array.
// ---------------------------------------------------------------------------
__global__ void gat_finalize_kernel(const float* __restrict__ s1, const float* __restrict__ s2,
                                    const float* __restrict__ blkmax,
                                    float* __restrict__ Z, float* __restrict__ Ai, float* __restrict__ Bi,
                                    float* __restrict__ Dj, float* __restrict__ Uj, float* __restrict__ Wj,
                                    int* __restrict__ rank)
{
    __shared__ float red[256];
    const int tid = threadIdx.x;
    red[tid] = fmaxf(blkmax[tid], blkmax[tid + 256]);
    __syncthreads();
    for (int s = 128; s > 0; s >>= 1) {
        if (tid < s) red[tid] = fmaxf(red[tid], red[tid + s]);
        __syncthreads();
    }
    const float s1max = red[0];
    for (int i = tid; i < NN; i += 256) {
        const float z  = s2[i] + s1max;
        const float mi = lrelu_(z);
        Z[i]  = z;
        Ai[i] = __expf(z - mi);
        Bi[i] = __expf(0.01f * z - mi);
        const float d = s1[i] - s1max;
        Dj[i] = d;
        Uj[i] = __expf(d);
        Wj[i] = __expf(0.01f * d);
        rank[i] = 0;
    }
}

// ---------------------------------------------------------------------------
// Rank: rank_j = #{k : d_k < d_j or (d_k == d_j and k < j)}. Exact permutation.
// grid (32, 8): x = j-chunk of 256, y = k-range of 1024. Partial counts via
// atomicAdd (integer, order-independent -> deterministic).
// ---------------------------------------------------------------------------
__global__ __launch_bounds__(256)
void rank_kernel(const float* __restrict__ Dj, int* __restrict__ rank)
{
    __shared__ float sd[1024];
    const int tid = threadIdx.x;
    const int j   = blockIdx.x * 256 + tid;
    const float dj = Dj[j];
    const int kbase = blockIdx.y * 1024;
    for (int i = tid; i < 1024; i += 256) sd[i] = Dj[kbase + i];
    __syncthreads();
    int cnt = 0;
    #pragma unroll 4
    for (int q = 0; q < 256; q++) {
        const float4 dk = ((const float4*)sd)[q];
        const int k0 = kbase + q * 4;
        cnt += (dk.x < dj || (dk.x == dj && k0     < j)) ? 1 : 0;
        cnt += (dk.y < dj || (dk.y == dj && k0 + 1 < j)) ? 1 : 0;
        cnt += (dk.z < dj || (dk.z == dj && k0 + 2 < j)) ? 1 : 0;
        cnt += (dk.w < dj || (dk.w == dj && k0 + 3 < j)) ? 1 : 0;
    }
    atomicAdd(&rank[j], cnt);
}

// ---------------------------------------------------------------------------
// Scatter into sorted order; premultiply rows by u / w.
// Block = 4 waves; each wave handles 8 j's, lane c writes row element c.
// ---------------------------------------------------------------------------
__global__ __launch_bounds__(256)
void scatter_kernel(const float* __restrict__ last,
                    const float* __restrict__ Dj, const float* __restrict__ Uj,
                    const float* __restrict__ Wj, const int* __restrict__ rank,
                    float* __restrict__ sortedRow, float* __restrict__ sortedD)
{
    const int tid = threadIdx.x;
    const int wv = tid >> 6, lane = tid & 63;
    #pragma unroll
    for (int it = 0; it < 8; it++) {
        const int j = blockIdx.x * 32 + wv * 8 + it;
        const int r = rank[j];
        const float u = Uj[j], w = Wj[j];
        const float lv = last[(size_t)j * HH + lane];
        float* row = sortedRow + (size_t)r * RS;
        row[lane]      = u * lv;
        row[64 + lane] = w * lv;
        if (lane == 0) {
            row[128] = u;
            row[129] = w;
            sortedD[r] = Dj[j];
        }
    }
}

// ---------------------------------------------------------------------------
// 130 independent scans over sorted order (one block per component).
// U-group (cols 0..63, 128): SUFFIX scan (reverse)  -> PP[t][c] = sum_{r>=t}
// W-group (cols 64..127, 129): PREFIX scan (forward)-> PP[t][c] = sum_{r<t}
// Suffix-direct (not total-prefix) keeps branch error ~40*eps relative.
// ---------------------------------------------------------------------------
__global__ __launch_bounds__(256)
void scan_kernel(const float* __restrict__ sortedRow, float* __restrict__ PP)
{
    __shared__ float wsum[4];
    const int c = blockIdx.x;                 // 0..129
    const bool rev = (c < 64) || (c == 128);  // U-group
    const int tid = threadIdx.x;
    const int wv = tid >> 6, lane = tid & 63;
    float carry = 0.f;
    if (tid == 0) PP[(size_t)(rev ? NN : 0) * RS + c] = 0.f;
    for (int chunk = 0; chunk < NN / 256; chunk++) {
        const int p = chunk * 256 + tid;          // forward position
        const int k = rev ? (NN - 1 - p) : p;     // rank index
        float v = sortedRow[(size_t)k * RS + c];
        #pragma unroll
        for (int d = 1; d < 64; d <<= 1) {
            const float t = __shfl_up(v, d);
            if (lane >= d) v += t;
        }
        if (lane == 63) wsum[wv] = v;
        __syncthreads();
        float off = carry;
        for (int w = 0; w < wv; w++) off += wsum[w];
        const int outIdx = rev ? k : (p + 1);
        PP[(size_t)outIdx * RS + c] = v + off;
        carry += wsum[0] + wsum[1] + wsum[2] + wsum[3];
        __syncthreads();
    }
}

// ---------------------------------------------------------------------------
// Apply: per i, binary-search threshold rank t (same fp32 predicate as the
// dense version -> identical partition), combine branch sums, add residual.
// Wave per i; 4 interleaved searches for latency hiding.
// ---------------------------------------------------------------------------
__global__ __launch_bounds__(256)
void apply_kernel(const float* __restrict__ last,
                  const float* __restrict__ Z, const float* __restrict__ Ai, const float* __restrict__ Bi,
                  const float* __restrict__ sortedD, const float* __restrict__ PP,
                  float* __restrict__ gout)
{
    const int tid = threadIdx.x;
    const int wv = tid >> 6, lane = tid & 63;
    const int base_i = (blockIdx.x * 4 + wv) * 8;
    for (int batch = 0; batch < 2; batch++) {
        const int i0 = base_i + batch * 4;
        float zi[4]; int lo[4], hi[4];
        #pragma unroll
        for (int q = 0; q < 4; q++) { zi[q] = Z[i0 + q]; lo[q] = 0; hi[q] = NN; }
        for (int iter = 0; iter < 13; iter++) {
            #pragma unroll
            for (int q = 0; q < 4; q++) {
                if (lo[q] < hi[q]) {
                    const int mid = (lo[q] + hi[q]) >> 1;
                    const float dm = sortedD[mid];
                    if (zi[q] + dm > 0.f) hi[q] = mid; else lo[q] = mid + 1;
                }
            }
        }
        #pragma unroll
        for (int q = 0; q < 4; q++) {
            const int i = i0 + q;
            const int t = lo[q];
            const float ai = Ai[i], bi = Bi[i];
            const float* row = PP + (size_t)t * RS;
            const float pu  = row[lane];        // suffix of u*last
            const float pw  = row[64 + lane];   // prefix of w*last
            const float pud = row[128];
            const float pwd = row[129];
            const float numer = bi * pw + ai * pu;
            const float den   = bi * pwd + ai * pud;
            const float lv = last[(size_t)i * HH + lane];
            gout[(size_t)i * HH + lane] = numer / den + lv;
        }
    }
}

// ---------------------------------------------------------------------------
// FC head (unchanged).
// ---------------------------------------------------------------------------
__global__ void fc_out_kernel(const float* __restrict__ gout,
                              const float* __restrict__ Wfc, const float* __restrict__ bfc,
                              const float* __restrict__ Wout, const float* __restrict__ bout,
                              float* __restrict__ out)
{
    __shared__ float sW[HH][HH + 1];
    __shared__ float sb[HH], sa[HH];
    const int tid = threadIdx.x;
    for (int idx = tid; idx < HH * HH; idx += 256) {
        const int h = idx >> 6, d = idx & 63;
        sW[d][h] = Wfc[idx];
    }
    if (tid < HH) { sb[tid] = bfc[tid]; sa[tid] = Wout[tid]; }
    __syncthreads();
    const int w = tid >> 6, l = tid & 63;
    const float bo = bout[0];
    int n = blockIdx.x * 8 + w * 2;
    for (int rep = 0; rep < 2; rep++, n++) {
        const float vl = gout[(size_t)n * HH + l];
        float acc = sb[l];
        #pragma unroll
        for (int d = 0; d < HH; d++) acc += __shfl(vl, d) * sW[d][l];
        float prod = lrelu_(acc) * sa[l];
        #pragma unroll
        for (int off = 32; off > 0; off >>= 1) prod += __shfl_xor(prod, off);
        if (l == 0) out[n] = prod + bo;
    }
}

extern "C" void kernel_launch(void* const* d_in, const int* in_sizes, int n_in,
                              void* d_out, int out_size, void* d_ws, size_t ws_size,
                              hipStream_t stream)
{
    (void)in_sizes; (void)n_in; (void)out_size; (void)ws_size;
    const float* x    = (const float*)d_in[0];
    const float* Wih0 = (const float*)d_in[1];
    const float* Whh0 = (const float*)d_in[2];
    const float* bih0 = (const float*)d_in[3];
    const float* bhh0 = (const float*)d_in[4];
    const float* Wih1 = (const float*)d_in[5];
    const float* Whh1 = (const float*)d_in[6];
    const float* bih1 = (const float*)d_in[7];
    const float* bhh1 = (const float*)d_in[8];
    const float* Wt   = (const float*)d_in[9];
    const float* bt   = (const float*)d_in[10];
    const float* a    = (const float*)d_in[11];
    const float* Wfc  = (const float*)d_in[12];
    const float* bfc  = (const float*)d_in[13];
    const float* Wout = (const float*)d_in[14];
    const float* bout = (const float*)d_in[15];
    float* out = (float*)d_out;

    float* ws        = (float*)d_ws;
    float* last      = ws;                        // N*H
    float* gout      = last + (size_t)NN*HH;      // N*H
    float* s1        = gout + (size_t)NN*HH;      // N
    float* s2        = s1 + NN;
    float* Z         = s2 + NN;
    float* Ai        = Z + NN;
    float* Bi        = Ai + NN;
    float* Dj        = Bi + NN;
    float* Uj        = Dj + NN;
    float* Wj        = Uj + NN;
    float* blkmax    = Wj + NN;                   // 512
    int*   rank      = (int*)(blkmax + 512);      // N ints
    float* sortedD   = (float*)(rank + NN);       // N
    float* sortedRow = sortedD + NN;              // N*RS
    float* PP        = sortedRow + (size_t)NN*RS; // (N+1)*RS

    lstm_fused_kernel<<<dim3(NN / 16), dim3(256), 0, stream>>>(
        x, Wih0, Whh0, bih0, bhh0, Wih1, Whh1, bih1, bhh1, last);
    gat_prep_kernel<<<dim3(NN / 16), dim3(256), 0, stream>>>(
        last, Wt, bt, a, s1, s2, blkmax);
    gat_finalize_kernel<<<dim3(1), dim3(256), 0, stream>>>(
        s1, s2, blkmax, Z, Ai, Bi, Dj, Uj, Wj, rank);
    rank_kernel<<<dim3(NN / 256, 8), dim3(256), 0, stream>>>(Dj, rank);
    scatter_kernel<<<dim3(NN / 32), dim3(256), 0, stream>>>(
        last, Dj, Uj, Wj, rank, sortedRow, sortedD);
    scan_kernel<<<dim3(130), dim3(256), 0, stream>>>(sortedRow, PP);
    apply_kernel<<<dim3(NN / 32), dim3(256), 0, stream>>>(
        last, Z, Ai, Bi, sortedD, PP, gout);
    fc_out_kernel<<<dim3(NN / 8), dim3(256), 0, stream>>>(
        gout, Wfc, bfc, Wout, bout, out);
}

// Round 5
// 287.944 us; speedup vs baseline: 8.5103x; 1.3466x over previous
//
#include <hip/hip_runtime.h>

#define NN 8192
#define TT 60
#define DF 6
#define HH 64
#define GG 256   // 4*H
#define RS 132   // sorted-row stride: [0..63] u*last, [64..127] w*last, [128] u, [129] w
#define CH 128   // scan chunk rows
#define NCH (NN / CH)   // 64 chunks

typedef _Float16 half8 __attribute__((ext_vector_type(8)));
typedef float f32x4 __attribute__((ext_vector_type(4)));
#define MFMA16(a, b, c) __builtin_amdgcn_mfma_f32_16x16x32_f16((a), (b), (c), 0, 0, 0)

// Fast activations: v_rcp_f32 (~1 ulp) instead of IEEE div sequence (~10 instrs).
__device__ __forceinline__ float sigmoidf_(float x) {
    return __builtin_amdgcn_rcpf(1.0f + __expf(-x));
}
__device__ __forceinline__ float tanhf_(float x) {
    return __builtin_fmaf(2.0f, __builtin_amdgcn_rcpf(1.0f + __expf(-2.0f * x)), -1.0f);
}
__device__ __forceinline__ float lrelu_(float x) { return x > 0.0f ? x : 0.01f * x; }

__device__ __forceinline__ half8 ldw8(const float* __restrict__ p) {
    const float4* q = (const float4*)p;
    float4 u = q[0], v = q[1];
    half8 r;
    r[0]=(_Float16)u.x; r[1]=(_Float16)u.y; r[2]=(_Float16)u.z; r[3]=(_Float16)u.w;
    r[4]=(_Float16)v.x; r[5]=(_Float16)v.y; r[6]=(_Float16)v.z; r[7]=(_Float16)v.w;
    return r;
}

// ---------------------------------------------------------------------------
// MFMA 2-layer LSTM. Block = 16 rows, 4 waves. (Structure as R2/R3; only the
// activation math changed: rcp instead of IEEE div.)
// ---------------------------------------------------------------------------
#define SXW (TT * 8 + 8)

__global__ __launch_bounds__(256, 2)
void lstm_fused_kernel(const float* __restrict__ x,
                       const float* __restrict__ Wih0, const float* __restrict__ Whh0,
                       const float* __restrict__ bih0, const float* __restrict__ bhh0,
                       const float* __restrict__ Wih1, const float* __restrict__ Whh1,
                       const float* __restrict__ bih1, const float* __restrict__ bhh1,
                       float* __restrict__ last_out)
{
    __shared__ _Float16 sxp[16][SXW];
    __shared__ _Float16 h0buf[2][16][72];
    __shared__ _Float16 h1buf[2][16][72];
    __shared__ _Float16 zero16[8];

    const int tid  = threadIdx.x;
    const int w    = tid >> 6;
    const int lane = tid & 63;
    const int quad = lane >> 4;
    const int l15  = lane & 15;
    const int hc   = w * 16 + l15;
    const int n0   = blockIdx.x * 16;

    for (int i = tid; i < 16 * SXW / 2; i += 256) ((unsigned*)sxp)[i] = 0u;
    for (int i = tid; i < 2 * 16 * 72 / 2; i += 256) ((unsigned*)h0buf)[i] = 0u;
    for (int i = tid; i < 2 * 16 * 72 / 2; i += 256) ((unsigned*)h1buf)[i] = 0u;
    if (tid < 4) ((unsigned*)zero16)[tid] = 0u;
    __syncthreads();

    for (int idx = tid; idx < 16 * TT * DF; idx += 256) {
        const int m = idx / (TT * DF);
        const int r = idx - m * (TT * DF);
        const int t = r / DF;
        const int d = r - t * DF;
        sxp[m][t * 8 + d] = (_Float16)x[(size_t)(n0 + m) * (TT * DF) + r];
    }

    half8 bhh0f[4][2], bih1f[4][2], bhh1f[4][2], bxf[4];
    float bias0[4], bias1[4];
    #pragma unroll
    for (int nt = 0; nt < 4; nt++) {
        const int g = nt * 64 + hc;
        #pragma unroll
        for (int kc = 0; kc < 2; kc++) {
            const int k0 = kc * 32 + quad * 8;
            bhh0f[nt][kc] = ldw8(Whh0 + (size_t)g * HH + k0);
            bih1f[nt][kc] = ldw8(Wih1 + (size_t)g * HH + k0);
            bhh1f[nt][kc] = ldw8(Whh1 + (size_t)g * HH + k0);
        }
        bias0[nt] = bih0[g] + bhh0[g];
        bias1[nt] = bih1[g] + bhh1[g];
        half8 t;
        #pragma unroll
        for (int j = 0; j < 8; j++) t[j] = (_Float16)0.f;
        if (quad == 0) {
            #pragma unroll
            for (int j = 0; j < DF; j++) t[j] = (_Float16)Wih0[g * DF + j];
        }
        bxf[nt] = t;
    }

    float c0[4] = {0.f, 0.f, 0.f, 0.f};
    float c1[4] = {0.f, 0.f, 0.f, 0.f};
    __syncthreads();

    int p = 0;
    for (int t = 0; t < TT; t++) {
        const half8 a_h0_0 = *(const half8*)&h0buf[p][l15][quad * 8];
        const half8 a_h0_1 = *(const half8*)&h0buf[p][l15][32 + quad * 8];
        const half8 a_h1_0 = *(const half8*)&h1buf[p][l15][quad * 8];
        const half8 a_h1_1 = *(const half8*)&h1buf[p][l15][32 + quad * 8];
        const _Float16* xap = (quad == 0) ? &sxp[l15][t * 8] : zero16;
        const half8 ax = *(const half8*)xap;

        f32x4 g0v[4];
        #pragma unroll
        for (int nt = 0; nt < 4; nt++) {
            f32x4 c; c[0] = bias0[nt]; c[1] = bias0[nt]; c[2] = bias0[nt]; c[3] = bias0[nt];
            c = MFMA16(ax, bxf[nt], c);
            c = MFMA16(a_h0_0, bhh0f[nt][0], c);
            c = MFMA16(a_h0_1, bhh0f[nt][1], c);
            g0v[nt] = c;
        }
        _Float16 (*h0w)[72] = h0buf[p ^ 1];
        #pragma unroll
        for (int reg = 0; reg < 4; reg++) {
            const float gi = g0v[0][reg], gf = g0v[1][reg], gc = g0v[2][reg], go = g0v[3][reg];
            const float cc = sigmoidf_(gf) * c0[reg] + sigmoidf_(gi) * tanhf_(gc);
            c0[reg] = cc;
            h0w[quad * 4 + reg][hc] = (_Float16)(sigmoidf_(go) * tanhf_(cc));
        }
        __syncthreads();

        const half8 a_h0n_0 = *(const half8*)&h0buf[p ^ 1][l15][quad * 8];
        const half8 a_h0n_1 = *(const half8*)&h0buf[p ^ 1][l15][32 + quad * 8];
        f32x4 g1v[4];
        #pragma unroll
        for (int nt = 0; nt < 4; nt++) {
            f32x4 c; c[0] = bias1[nt]; c[1] = bias1[nt]; c[2] = bias1[nt]; c[3] = bias1[nt];
            c = MFMA16(a_h0n_0, bih1f[nt][0], c);
            c = MFMA16(a_h0n_1, bih1f[nt][1], c);
            c = MFMA16(a_h1_0, bhh1f[nt][0], c);
            c = MFMA16(a_h1_1, bhh1f[nt][1], c);
            g1v[nt] = c;
        }
        _Float16 (*h1w)[72] = h1buf[p ^ 1];
        #pragma unroll
        for (int reg = 0; reg < 4; reg++) {
            const float gi = g1v[0][reg], gf = g1v[1][reg], gc = g1v[2][reg], go = g1v[3][reg];
            const float cc = sigmoidf_(gf) * c1[reg] + sigmoidf_(gi) * tanhf_(gc);
            c1[reg] = cc;
            const float hv = sigmoidf_(go) * tanhf_(cc);
            h1w[quad * 4 + reg][hc] = (_Float16)hv;
            if (t == TT - 1) last_out[(size_t)(n0 + quad * 4 + reg) * HH + hc] = hv;
        }
        __syncthreads();
        p ^= 1;
    }
}

// ---------------------------------------------------------------------------
// GAT prep (unchanged): s1, s2, per-block max of s1.
// ---------------------------------------------------------------------------
__global__ void gat_prep_kernel(const float* __restrict__ last,
                                const float* __restrict__ Wt, const float* __restrict__ bt,
                                const float* __restrict__ a,
                                float* __restrict__ s1, float* __restrict__ s2,
                                float* __restrict__ blkmax)
{
    __shared__ float sWtT[HH][HH + 1];
    __shared__ float slast[16][HH];
    __shared__ float sbt[HH], sa1[HH], sa2[HH];
    __shared__ float swm[4];
    const int tid = threadIdx.x;
    for (int idx = tid; idx < HH * HH; idx += 256) {
        const int h = idx >> 6, d = idx & 63;
        sWtT[d][h] = Wt[idx];
    }
    if (tid < HH) { sbt[tid] = bt[tid]; sa1[tid] = a[tid]; sa2[tid] = a[HH + tid]; }
    const int n0 = blockIdx.x * 16;
    for (int idx = tid; idx < 16 * HH; idx += 256)
        (&slast[0][0])[idx] = last[(size_t)n0 * HH + idx];
    __syncthreads();
    const int w = tid >> 6, l = tid & 63;
    float wmax = -1e30f;
    for (int rr = 0; rr < 4; rr++) {
        const int r = w * 4 + rr;
        float acc = sbt[l];
        #pragma unroll
        for (int d = 0; d < HH; d++) acc += slast[r][d] * sWtT[d][l];
        float p1 = acc * sa1[l], p2 = acc * sa2[l];
        #pragma unroll
        for (int off = 32; off > 0; off >>= 1) {
            p1 += __shfl_xor(p1, off);
            p2 += __shfl_xor(p2, off);
        }
        if (l == 0) { s1[n0 + r] = p1; s2[n0 + r] = p2; }
        wmax = fmaxf(wmax, p1);
    }
    if (l == 0) swm[w] = wmax;
    __syncthreads();
    if (tid == 0) blkmax[blockIdx.x] = fmaxf(fmaxf(swm[0], swm[1]), fmaxf(swm[2], swm[3]));
}

// ---------------------------------------------------------------------------
// Finalize (grid=32): each block redundantly reduces blkmax, then handles
// a strided slice of the N elementwise factors.
// ---------------------------------------------------------------------------
__global__ void gat_finalize_kernel(const float* __restrict__ s1, const float* __restrict__ s2,
                                    const float* __restrict__ blkmax,
                                    float* __restrict__ Z, float* __restrict__ Ai, float* __restrict__ Bi,
                                    float* __restrict__ Dj, float* __restrict__ Uj, float* __restrict__ Wj,
                                    int* __restrict__ rank)
{
    __shared__ float red[256];
    const int tid = threadIdx.x;
    red[tid] = fmaxf(blkmax[tid], blkmax[tid + 256]);
    __syncthreads();
    for (int s = 128; s > 0; s >>= 1) {
        if (tid < s) red[tid] = fmaxf(red[tid], red[tid + s]);
        __syncthreads();
    }
    const float s1max = red[0];
    for (int i = blockIdx.x * 256 + tid; i < NN; i += 256 * 32) {
        const float z  = s2[i] + s1max;
        const float mi = lrelu_(z);
        Z[i]  = z;
        Ai[i] = __expf(z - mi);
        Bi[i] = __expf(0.01f * z - mi);
        const float d = s1[i] - s1max;
        Dj[i] = d;
        Uj[i] = __expf(d);
        Wj[i] = __expf(0.01f * d);
        rank[i] = 0;
    }
}

// ---------------------------------------------------------------------------
// Rank (unchanged): rank_j = #{k : d_k < d_j or (d_k == d_j and k < j)}.
// ---------------------------------------------------------------------------
__global__ __launch_bounds__(256)
void rank_kernel(const float* __restrict__ Dj, int* __restrict__ rank)
{
    __shared__ float sd[1024];
    const int tid = threadIdx.x;
    const int j   = blockIdx.x * 256 + tid;
    const float dj = Dj[j];
    const int kbase = blockIdx.y * 1024;
    for (int i = tid; i < 1024; i += 256) sd[i] = Dj[kbase + i];
    __syncthreads();
    int cnt = 0;
    #pragma unroll 4
    for (int q = 0; q < 256; q++) {
        const float4 dk = ((const float4*)sd)[q];
        const int k0 = kbase + q * 4;
        cnt += (dk.x < dj || (dk.x == dj && k0     < j)) ? 1 : 0;
        cnt += (dk.y < dj || (dk.y == dj && k0 + 1 < j)) ? 1 : 0;
        cnt += (dk.z < dj || (dk.z == dj && k0 + 2 < j)) ? 1 : 0;
        cnt += (dk.w < dj || (dk.w == dj && k0 + 3 < j)) ? 1 : 0;
    }
    atomicAdd(&rank[j], cnt);
}

// ---------------------------------------------------------------------------
// Scatter (unchanged, row-major).
// ---------------------------------------------------------------------------
__global__ __launch_bounds__(256)
void scatter_kernel(const float* __restrict__ last,
                    const float* __restrict__ Dj, const float* __restrict__ Uj,
                    const float* __restrict__ Wj, const int* __restrict__ rank,
                    float* __restrict__ sortedRow, float* __restrict__ sortedD)
{
    const int tid = threadIdx.x;
    const int wv = tid >> 6, lane = tid & 63;
    #pragma unroll
    for (int it = 0; it < 8; it++) {
        const int j = blockIdx.x * 32 + wv * 8 + it;
        const int r = rank[j];
        const float u = Uj[j], w = Wj[j];
        const float lv = last[(size_t)j * HH + lane];
        float* row = sortedRow + (size_t)r * RS;
        row[lane]      = u * lv;
        row[64 + lane] = w * lv;
        if (lane == 0) {
            row[128] = u;
            row[129] = w;
            sortedD[r] = Dj[j];
        }
    }
}

// ---------------------------------------------------------------------------
// 3-phase hierarchical scan, fully coalesced.
// scanA: per-chunk column sums. Block b sums rows [b*CH, b*CH+CH).
// Thread c (<130) owns column c; reads at fixed r are coalesced across c.
// ---------------------------------------------------------------------------
__global__ __launch_bounds__(256)
void scanA_kernel(const float* __restrict__ sortedRow, float* __restrict__ chunkSum)
{
    const int c = threadIdx.x;
    if (c >= 130) return;
    const int b = blockIdx.x;
    const float* base = sortedRow + (size_t)b * CH * RS + c;
    float s = 0.f;
    #pragma unroll 8
    for (int r = 0; r < CH; r++) s += base[(size_t)r * RS];
    chunkSum[b * RS + c] = s;
}

// ---------------------------------------------------------------------------
// scanB: one block scans the NCH chunk sums per column.
// U-group (c<64 or c==128): chunkOfs[b] = sum over chunks > b (for suffix).
// W-group: chunkOfs[b] = sum over chunks < b (exclusive prefix).
// ---------------------------------------------------------------------------
__global__ __launch_bounds__(256)
void scanB_kernel(const float* __restrict__ chunkSum, float* __restrict__ chunkOfs)
{
    const int c = threadIdx.x;
    if (c >= 130) return;
    const bool rev = (c < 64) || (c == 128);
    float run = 0.f;
    if (rev) {
        for (int b = NCH - 1; b >= 0; b--) { chunkOfs[b * RS + c] = run; run += chunkSum[b * RS + c]; }
    } else {
        for (int b = 0; b < NCH; b++)      { chunkOfs[b * RS + c] = run; run += chunkSum[b * RS + c]; }
    }
}

// ---------------------------------------------------------------------------
// scanC: fill PP. U-group: PP[t][c] = suffix sum over rows >= t (descending
// walk). W-group: PP[t][c] = exclusive prefix over rows < t (ascending walk).
// Boundary row t=NN: U=0, W=total (written by block NCH-1).
// ---------------------------------------------------------------------------
__global__ __launch_bounds__(256)
void scanC_kernel(const float* __restrict__ sortedRow, const float* __restrict__ chunkOfs,
                  float* __restrict__ PP)
{
    const int c = threadIdx.x;
    if (c >= 130) return;
    const int b = blockIdx.x;
    const bool rev = (c < 64) || (c == 128);
    float run = chunkOfs[b * RS + c];
    if (rev) {
        if (b == NCH - 1) PP[(size_t)NN * RS + c] = 0.f;
        for (int r = CH - 1; r >= 0; r--) {
            const size_t t = (size_t)b * CH + r;
            run += sortedRow[t * RS + c];
            PP[t * RS + c] = run;
        }
    } else {
        for (int r = 0; r < CH; r++) {
            const size_t t = (size_t)b * CH + r;
            PP[t * RS + c] = run;
            run += sortedRow[t * RS + c];
        }
        if (b == NCH - 1) PP[(size_t)NN * RS + c] = run;
    }
}

// ---------------------------------------------------------------------------
// Apply (rcp for final divide; otherwise unchanged).
// ---------------------------------------------------------------------------
__global__ __launch_bounds__(256)
void apply_kernel(const float* __restrict__ last,
                  const float* __restrict__ Z, const float* __restrict__ Ai, const float* __restrict__ Bi,
                  const float* __restrict__ sortedD, const float* __restrict__ PP,
                  float* __restrict__ gout)
{
    const int tid = threadIdx.x;
    const int wv = tid >> 6, lane = tid & 63;
    const int base_i = (blockIdx.x * 4 + wv) * 8;
    for (int batch = 0; batch < 2; batch++) {
        const int i0 = base_i + batch * 4;
        float zi[4]; int lo[4], hi[4];
        #pragma unroll
        for (int q = 0; q < 4; q++) { zi[q] = Z[i0 + q]; lo[q] = 0; hi[q] = NN; }
        for (int iter = 0; iter < 13; iter++) {
            #pragma unroll
            for (int q = 0; q < 4; q++) {
                if (lo[q] < hi[q]) {
                    const int mid = (lo[q] + hi[q]) >> 1;
                    const float dm = sortedD[mid];
                    if (zi[q] + dm > 0.f) hi[q] = mid; else lo[q] = mid + 1;
                }
            }
        }
        #pragma unroll
        for (int q = 0; q < 4; q++) {
            const int i = i0 + q;
            const int t = lo[q];
            const float ai = Ai[i], bi = Bi[i];
            const float* row = PP + (size_t)t * RS;
            const float pu  = row[lane];
            const float pw  = row[64 + lane];
            const float pud = row[128];
            const float pwd = row[129];
            const float numer = bi * pw + ai * pu;
            const float den   = bi * pwd + ai * pud;
            const float lv = last[(size_t)i * HH + lane];
            gout[(size_t)i * HH + lane] = numer * __builtin_amdgcn_rcpf(den) + lv;
        }
    }
}

// ---------------------------------------------------------------------------
// FC head (unchanged).
// ---------------------------------------------------------------------------
__global__ void fc_out_kernel(const float* __restrict__ gout,
                              const float* __restrict__ Wfc, const float* __restrict__ bfc,
                              const float* __restrict__ Wout, const float* __restrict__ bout,
                              float* __restrict__ out)
{
    __shared__ float sW[HH][HH + 1];
    __shared__ float sb[HH], sa[HH];
    const int tid = threadIdx.x;
    for (int idx = tid; idx < HH * HH; idx += 256) {
        const int h = idx >> 6, d = idx & 63;
        sW[d][h] = Wfc[idx];
    }
    if (tid < HH) { sb[tid] = bfc[tid]; sa[tid] = Wout[tid]; }
    __syncthreads();
    const int w = tid >> 6, l = tid & 63;
    const float bo = bout[0];
    int n = blockIdx.x * 8 + w * 2;
    for (int rep = 0; rep < 2; rep++, n++) {
        const float vl = gout[(size_t)n * HH + l];
        float acc = sb[l];
        #pragma unroll
        for (int d = 0; d < HH; d++) acc += __shfl(vl, d) * sW[d][l];
        float prod = lrelu_(acc) * sa[l];
        #pragma unroll
        for (int off = 32; off > 0; off >>= 1) prod += __shfl_xor(prod, off);
        if (l == 0) out[n] = prod + bo;
    }
}

extern "C" void kernel_launch(void* const* d_in, const int* in_sizes, int n_in,
                              void* d_out, int out_size, void* d_ws, size_t ws_size,
                              hipStream_t stream)
{
    (void)in_sizes; (void)n_in; (void)out_size; (void)ws_size;
    const float* x    = (const float*)d_in[0];
    const float* Wih0 = (const float*)d_in[1];
    const float* Whh0 = (const float*)d_in[2];
    const float* bih0 = (const float*)d_in[3];
    const float* bhh0 = (const float*)d_in[4];
    const float* Wih1 = (const float*)d_in[5];
    const float* Whh1 = (const float*)d_in[6];
    const float* bih1 = (const float*)d_in[7];
    const float* bhh1 = (const float*)d_in[8];
    const float* Wt   = (const float*)d_in[9];
    const float* bt   = (const float*)d_in[10];
    const float* a    = (const float*)d_in[11];
    const float* Wfc  = (const float*)d_in[12];
    const float* bfc  = (const float*)d_in[13];
    const float* Wout = (const float*)d_in[14];
    const float* bout = (const float*)d_in[15];
    float* out = (float*)d_out;

    float* ws        = (float*)d_ws;
    float* last      = ws;                        // N*H
    float* gout      = last + (size_t)NN*HH;      // N*H
    float* s1        = gout + (size_t)NN*HH;      // N
    float* s2        = s1 + NN;
    float* Z         = s2 + NN;
    float* Ai        = Z + NN;
    float* Bi        = Ai + NN;
    float* Dj        = Bi + NN;
    float* Uj        = Dj + NN;
    float* Wj        = Uj + NN;
    float* blkmax    = Wj + NN;                   // 512
    int*   rank      = (int*)(blkmax + 512);      // N ints
    float* sortedD   = (float*)(rank + NN);       // N
    float* sortedRow = sortedD + NN;              // N*RS
    float* PP        = sortedRow + (size_t)NN*RS; // (N+1)*RS
    float* chunkSum  = PP + (size_t)(NN+1)*RS;    // NCH*RS
    float* chunkOfs  = chunkSum + NCH*RS;         // NCH*RS

    lstm_fused_kernel<<<dim3(NN / 16), dim3(256), 0, stream>>>(
        x, Wih0, Whh0, bih0, bhh0, Wih1, Whh1, bih1, bhh1, last);
    gat_prep_kernel<<<dim3(NN / 16), dim3(256), 0, stream>>>(
        last, Wt, bt, a, s1, s2, blkmax);
    gat_finalize_kernel<<<dim3(32), dim3(256), 0, stream>>>(
        s1, s2, blkmax, Z, Ai, Bi, Dj, Uj, Wj, rank);
    rank_kernel<<<dim3(NN / 256, 8), dim3(256), 0, stream>>>(Dj, rank);
    scatter_kernel<<<dim3(NN / 32), dim3(256), 0, stream>>>(
        last, Dj, Uj, Wj, rank, sortedRow, sortedD);
    scanA_kernel<<<dim3(NCH), dim3(256), 0, stream>>>(sortedRow, chunkSum);
    scanB_kernel<<<dim3(1), dim3(256), 0, stream>>>(chunkSum, chunkOfs);
    scanC_kernel<<<dim3(NCH), dim3(256), 0, stream>>>(sortedRow, chunkOfs, PP);
    apply_kernel<<<dim3(NN / 32), dim3(256), 0, stream>>>(
        last, Z, Ai, Bi, sortedD, PP, gout);
    fc_out_kernel<<<dim3(NN / 8), dim3(256), 0, stream>>>(
        gout, Wfc, bfc, Wout, bout, out);
}